// Round 2
// baseline (722.849 us; speedup 1.0000x reference)
//
#include <hip/hip_runtime.h>
#include <cstdint>
#include <cstddef>

// (B_, S, I, H) = (16, 2048, 256, 512)
#define BB 16
#define SS 2048
#define II 256
#define HH 512
#define NNC 1024           /* output row width = 2H (re || im) */
#define CHUNK 32           /* timesteps per block              */
#define NCHUNK 64          /* chunks per batch                 */
#define NBLK (BB * NCHUNK) /* 1024 blocks                      */

using bf16x8 = __attribute__((ext_vector_type(8))) short;
using f32x4  = __attribute__((ext_vector_type(4))) float;

__device__ __forceinline__ short f2bf(float f) {
    uint32_t u = __float_as_uint(f);
    u += 0x7fffu + ((u >> 16) & 1u);   // RTNE
    return (short)(u >> 16);
}
__device__ __forceinline__ unsigned long long packf2(float a, float b) {
    return (unsigned long long)__float_as_uint(a) |
           ((unsigned long long)__float_as_uint(b) << 32);
}

// ---- pack B_re (rows 0..511) / B_im (rows 512..1023) -> bf16 [1024][256] ----
__global__ __launch_bounds__(256) void cvt_b_kernel(const float* __restrict__ Bre,
                                                    const float* __restrict__ Bim,
                                                    short* __restrict__ Bc) {
    int i = blockIdx.x * 256 + threadIdx.x;   // 262,144 threads exactly
    float v = (i < HH * II) ? Bre[i] : Bim[i - HH * II];
    Bc[i] = f2bf(v);
}

// ---- reset lookback flags (must run before main kernel on EVERY launch) ----
__global__ __launch_bounds__(256) void zero_flags_kernel(int* __restrict__ flags) {
    flags[blockIdx.x * 256 + threadIdx.x] = 0;
}

// ---- fused GEMM + chunked scan with decoupled lookback ----
// Block = one (batch b, chunk c): rows m0..m0+31, all 1024 cols.
// 8 waves; wave w computes cols [64w,64w+64) re and [512+64w, ...) im
// = 16 MFMA 16x16 tiles, so each wave's threads own exactly their own
// scan columns after an in-wave LDS transpose. Thread tid owns complex
// state h = tid for its 32 timesteps, entirely in registers.
__global__ __launch_bounds__(512, 4) void lru_fused_kernel(
    const float* __restrict__ x,
    const short* __restrict__ Bc,
    const float* __restrict__ nu,
    const float* __restrict__ th,
    unsigned long long* __restrict__ Agg,
    unsigned long long* __restrict__ Inc,
    int* __restrict__ flags,
    float* __restrict__ out)
{
    __shared__ float lds[8][CHUNK * 64];   // 64 KiB: per-wave [32 t][64 col] f32

    const int blk = blockIdx.x;
    const int b   = blk >> 6;
    const int c   = blk & 63;
    const int tid = threadIdx.x;
    const int w   = tid >> 6;
    const int l   = tid & 63;
    const int fr  = l & 15;     // MFMA fragment row/col within 16
    const int fg  = l >> 4;     // MFMA k-group (0..3)
    const int h   = tid;        // this thread's complex state index
    const size_t m0 = (size_t)b * SS + (size_t)c * CHUNK;

    // ---------------- GEMM: Bx[32][1024] for this chunk ----------------
    f32x4 acc[2][8] = {};
#pragma unroll
    for (int kk = 0; kk < 8; ++kk) {            // K = 8 * 32
        bf16x8 a[2];
#pragma unroll
        for (int m = 0; m < 2; ++m) {           // two 16-row M tiles
            const float* ap = x + (m0 + (size_t)(m * 16 + fr)) * II + fg * 8 + kk * 32;
            float4 v0 = *(const float4*)ap;
            float4 v1 = *(const float4*)(ap + 4);
            bf16x8 t;
            t[0]=f2bf(v0.x); t[1]=f2bf(v0.y); t[2]=f2bf(v0.z); t[3]=f2bf(v0.w);
            t[4]=f2bf(v1.x); t[5]=f2bf(v1.y); t[6]=f2bf(v1.z); t[7]=f2bf(v1.w);
            a[m] = t;
        }
#pragma unroll
        for (int j = 0; j < 8; ++j) {           // wave's 8 col tiles (4 re + 4 im)
            const int nc = (j < 4) ? (4 * w + j) : (32 + 4 * w + (j - 4));
            const bf16x8 bf = *(const bf16x8*)(Bc + (size_t)(nc * 16 + fr) * II + fg * 8 + kk * 32);
            acc[0][j] = __builtin_amdgcn_mfma_f32_16x16x32_bf16(a[0], bf, acc[0][j], 0, 0, 0);
            acc[1][j] = __builtin_amdgcn_mfma_f32_16x16x32_bf16(a[1], bf, acc[1][j], 0, 0, 0);
        }
    }

    // ------------- in-wave transpose via per-wave LDS region -------------
    // D layout: col = lane&15, row(t) = (lane>>4)*4 + reg  [verified m89]
    float yre[CHUNK], yim[CHUNK];
    float* L = lds[w];
    // pass 1: re tiles (j = 0..3) -> local cols 0..63
#pragma unroll
    for (int j = 0; j < 4; ++j)
#pragma unroll
        for (int m = 0; m < 2; ++m)
#pragma unroll
            for (int r = 0; r < 4; ++r)
                L[(m * 16 + fg * 4 + r) * 64 + j * 16 + fr] = acc[m][j][r];
    __syncthreads();
#pragma unroll
    for (int t = 0; t < CHUNK; ++t) yre[t] = L[t * 64 + l];
    __syncthreads();
    // pass 2: im tiles (j = 4..7)
#pragma unroll
    for (int j = 4; j < 8; ++j)
#pragma unroll
        for (int m = 0; m < 2; ++m)
#pragma unroll
            for (int r = 0; r < 4; ++r)
                L[(m * 16 + fg * 4 + r) * 64 + (j - 4) * 16 + fr] = acc[m][j][r];
    __syncthreads();
#pragma unroll
    for (int t = 0; t < CHUNK; ++t) yim[t] = L[t * 64 + l];

    // ---------------- lambda constants for this h ----------------
    const float env  = __expf(nu[h]);
    const float rad  = __expf(-env);
    const float lre  = rad * __cosf(th[h]);
    const float lim_ = rad * __sinf(th[h]);
    const float r32  = __expf(-32.0f * env);         // |lam|^32
    const float a32  = 32.0f * th[h];
    const float l32re = r32 * __cosf(a32);
    const float l32im = r32 * __sinf(a32);

    // ---------------- local scan (h0 = 0) ----------------
    float hre = 0.f, him = 0.f;
#pragma unroll
    for (int t = 0; t < CHUNK; ++t) {
        float nr = lre * hre - lim_ * him + yre[t];
        float ni = lre * him + lim_ * hre + yim[t];
        hre = nr; him = ni;
        yre[t] = hre; yim[t] = him;
    }

    // ---------------- publish + decoupled lookback ----------------
    const size_t vidx = (size_t)blk * HH + h;
    float pR = 0.f, pI = 0.f;                     // carry entering this chunk
    if (c == 0) {
        __hip_atomic_store(&Inc[vidx], packf2(yre[31], yim[31]),
                           __ATOMIC_RELAXED, __HIP_MEMORY_SCOPE_AGENT);
        __syncthreads();                          // drains vmcnt for all threads
        if (tid == 0)
            __hip_atomic_store(&flags[blk], 2, __ATOMIC_RELEASE, __HIP_MEMORY_SCOPE_AGENT);
    } else {
        __hip_atomic_store(&Agg[vidx], packf2(yre[31], yim[31]),
                           __ATOMIC_RELAXED, __HIP_MEMORY_SCOPE_AGENT);
        __syncthreads();
        if (tid == 0)
            __hip_atomic_store(&flags[blk], 1, __ATOMIC_RELEASE, __HIP_MEMORY_SCOPE_AGENT);
        // lookback: P = A[c-1] + lam32*A[c-2] + ... + lam32^k * I[c-1-k]
        float mR = 1.f, mI = 0.f;
        int j = c - 1;
        while (true) {
            int f = 0;
            do {
                if (l == 0)
                    f = __hip_atomic_load(&flags[b * 64 + j],
                                          __ATOMIC_ACQUIRE, __HIP_MEMORY_SCOPE_AGENT);
                f = __shfl(f, 0);
                if (f == 0) __builtin_amdgcn_s_sleep(2);
            } while (f == 0);
            const unsigned long long* src = (f == 2) ? Inc : Agg;
            unsigned long long v = __hip_atomic_load(&src[(size_t)(b * 64 + j) * HH + h],
                                                     __ATOMIC_RELAXED, __HIP_MEMORY_SCOPE_AGENT);
            float vR = __uint_as_float((uint32_t)v);
            float vI = __uint_as_float((uint32_t)(v >> 32));
            pR += mR * vR - mI * vI;
            pI += mR * vI + mI * vR;
            if (f == 2) break;
            float nmR = mR * l32re - mI * l32im;
            mI = mR * l32im + mI * l32re;
            mR = nmR;
            --j;
        }
        // inclusive state of this chunk = E + lam32 * P
        float iR = yre[31] + l32re * pR - l32im * pI;
        float iI = yim[31] + l32re * pI + l32im * pR;
        __hip_atomic_store(&Inc[vidx], packf2(iR, iI),
                           __ATOMIC_RELAXED, __HIP_MEMORY_SCOPE_AGENT);
        __syncthreads();
        if (tid == 0)
            __hip_atomic_store(&flags[blk], 2, __ATOMIC_RELEASE, __HIP_MEMORY_SCOPE_AGENT);
    }

    // ---------------- fixup (y_t += lam^{t+1} * P) + final store ----------------
    float zR = pR, zI = pI;
    float* ob = out + m0 * NNC;
#pragma unroll
    for (int t = 0; t < CHUNK; ++t) {
        float nzR = lre * zR - lim_ * zI;
        zI = lre * zI + lim_ * zR;
        zR = nzR;
        ob[(size_t)t * NNC + h]      = yre[t] + zR;
        ob[(size_t)t * NNC + HH + h] = yim[t] + zI;
    }
}

extern "C" void kernel_launch(void* const* d_in, const int* in_sizes, int n_in,
                              void* d_out, int out_size, void* d_ws, size_t ws_size,
                              hipStream_t stream) {
    const float* x   = (const float*)d_in[0];
    const float* nu  = (const float*)d_in[1];
    const float* th  = (const float*)d_in[2];
    const float* Bre = (const float*)d_in[3];
    const float* Bim = (const float*)d_in[4];
    float* out = (float*)d_out;

    // ws layout: Agg (4 MiB) | Inc (4 MiB) | Bc bf16 (512 KiB) | flags (4 KiB)
    char* ws = (char*)d_ws;
    unsigned long long* Agg = (unsigned long long*)ws;
    unsigned long long* Inc = Agg + (size_t)NBLK * HH;
    short* Bc  = (short*)(Inc + (size_t)NBLK * HH);
    int* flags = (int*)((char*)Bc + (size_t)NNC * II * 2);

    cvt_b_kernel<<<(NNC * II) / 256, 256, 0, stream>>>(Bre, Bim, Bc);
    zero_flags_kernel<<<NBLK / 256, 256, 0, stream>>>(flags);
    lru_fused_kernel<<<NBLK, 512, 0, stream>>>(x, Bc, nu, th, Agg, Inc, flags, out);
}

// Round 3
// 154.759 us; speedup vs baseline: 4.6708x; 4.6708x over previous
//
#include <hip/hip_runtime.h>
#include <cstdint>
#include <cstddef>

// (B_, S, I, H) = (16, 2048, 256, 512)
#define BB 16
#define SS 2048
#define II 256
#define HH 512
#define NNC 1024           /* output row width = 2H (re || im) */
#define CHUNK 32           /* timesteps per block              */
#define NCHUNK 64          /* chunks per batch                 */
#define NBLK (BB * NCHUNK) /* 1024 blocks                      */

using half8  = __attribute__((ext_vector_type(8))) _Float16;
using half2v = __attribute__((ext_vector_type(2))) _Float16;
using f32x4  = __attribute__((ext_vector_type(4))) float;

// ---- pack B_re (rows 0..511) / B_im (rows 512..1023) -> f16 [1024][256] ----
__global__ __launch_bounds__(256) void cvt_b_kernel(const float* __restrict__ Bre,
                                                    const float* __restrict__ Bim,
                                                    _Float16* __restrict__ Bc) {
    int i = blockIdx.x * 256 + threadIdx.x;   // 262,144 threads exactly
    float v = (i < HH * II) ? Bre[i] : Bim[i - HH * II];
    Bc[i] = (_Float16)v;
}

// ---- K1: GEMM (f16 MFMA) + LDS transpose + local chunk scan ----
// Block = (batch b, chunk c): rows m0..m0+31, all 1024 cols.
// Wave w owns cols [64w,64w+64) re and [512+64w,...) im = 16 MFMA tiles.
// After per-wave LDS transpose, thread tid owns state h=tid; scans 32 steps
// while draining LDS, storing packed-f16 y into out's re-slots, and E at end.
__global__ __launch_bounds__(512, 4) void lru_gemm_scan_kernel(
    const float* __restrict__ x,
    const _Float16* __restrict__ Bc,
    const float* __restrict__ nu,
    const float* __restrict__ th,
    float2* __restrict__ E,
    uint32_t* __restrict__ outY)   // d_out viewed as u32 rows of 1024
{
    __shared__ float lds[8][CHUNK * 64];   // 64 KiB: per-wave [32 t][64 col]

    const int blk = blockIdx.x;
    const int b   = blk >> 6;
    const int c   = blk & 63;
    const int tid = threadIdx.x;
    const int w   = tid >> 6;
    const int l   = tid & 63;
    const int fr  = l & 15;     // MFMA fragment row/col within 16
    const int fg  = l >> 4;     // MFMA k-group (0..3)
    const int h   = tid;        // this thread's state index after transpose
    const size_t m0 = (size_t)b * SS + (size_t)c * CHUNK;

    // ---------------- GEMM: Bx[32][1024] for this chunk ----------------
    f32x4 acc[2][8] = {};
#pragma unroll
    for (int kk = 0; kk < 8; ++kk) {            // K = 8 * 32
        half8 a[2];
#pragma unroll
        for (int m = 0; m < 2; ++m) {
            const float* ap = x + (m0 + (size_t)(m * 16 + fr)) * II + fg * 8 + kk * 32;
            float4 v0 = *(const float4*)ap;
            float4 v1 = *(const float4*)(ap + 4);
            half8 t;
            t[0]=(_Float16)v0.x; t[1]=(_Float16)v0.y; t[2]=(_Float16)v0.z; t[3]=(_Float16)v0.w;
            t[4]=(_Float16)v1.x; t[5]=(_Float16)v1.y; t[6]=(_Float16)v1.z; t[7]=(_Float16)v1.w;
            a[m] = t;
        }
#pragma unroll
        for (int j = 0; j < 8; ++j) {           // 4 re tiles + 4 im tiles
            const int nc = (j < 4) ? (4 * w + j) : (32 + 4 * w + (j - 4));
            const half8 bf = *(const half8*)(Bc + (size_t)(nc * 16 + fr) * II + fg * 8 + kk * 32);
            acc[0][j] = __builtin_amdgcn_mfma_f32_16x16x32_f16(a[0], bf, acc[0][j], 0, 0, 0);
            acc[1][j] = __builtin_amdgcn_mfma_f32_16x16x32_f16(a[1], bf, acc[1][j], 0, 0, 0);
        }
    }

    // ------------- per-wave LDS transpose, two passes -------------
    // D layout: col = lane&15, row(t) = (lane>>4)*4 + reg  [verified]
    float* L = lds[w];
    // pass 1: re tiles (j=0..3) -> yre registers
#pragma unroll
    for (int j = 0; j < 4; ++j)
#pragma unroll
        for (int m = 0; m < 2; ++m)
#pragma unroll
            for (int r = 0; r < 4; ++r)
                L[(m * 16 + fg * 4 + r) * 64 + j * 16 + fr] = acc[m][j][r];
    __syncthreads();
    float yre[CHUNK];
#pragma unroll
    for (int t = 0; t < CHUNK; ++t) yre[t] = L[t * 64 + l];
    __syncthreads();
    // pass 2: im tiles (j=4..7)
#pragma unroll
    for (int j = 4; j < 8; ++j)
#pragma unroll
        for (int m = 0; m < 2; ++m)
#pragma unroll
            for (int r = 0; r < 4; ++r)
                L[(m * 16 + fg * 4 + r) * 64 + (j - 4) * 16 + fr] = acc[m][j][r];
    __syncthreads();

    // ---------------- lambda for this h ----------------
    const float env  = __expf(nu[h]);
    const float rad  = __expf(-env);
    const float lre  = rad * __cosf(th[h]);
    const float lim_ = rad * __sinf(th[h]);

    // ------- local scan (h0=0) fused with im-drain + packed store -------
    float hre = 0.f, him = 0.f;
#pragma unroll
    for (int t = 0; t < CHUNK; ++t) {
        const float vim = L[t * 64 + l];
        const float nr = lre * hre - lim_ * him + yre[t];
        const float ni = lre * him + lim_ * hre + vim;
        hre = nr; him = ni;
        union { half2v hh; uint32_t u; } pk;
        pk.hh[0] = (_Float16)hre;
        pk.hh[1] = (_Float16)him;
        outY[(m0 + (size_t)t) * NNC + h] = pk.u;
    }
    E[(size_t)blk * HH + h] = make_float2(hre, him);
}

// ---- K2: sequential carry across chunks; P[c] = state entering chunk c ----
__global__ __launch_bounds__(512) void scan_carry(const float2* __restrict__ E,
                                                  const float* __restrict__ nu,
                                                  const float* __restrict__ th,
                                                  float2* __restrict__ P) {
    const int b = blockIdx.x;          // 16
    const int h = threadIdx.x;         // 512
    const float en  = __expf(nu[h]);
    const float rL  = __expf(-(float)CHUNK * en);        // |lam|^CHUNK
    const float aL  = (float)CHUNK * th[h];
    const float lre = rL * __cosf(aL);
    const float lim = rL * __sinf(aL);
    float pre = 0.f, pim = 0.f;
#pragma unroll 4
    for (int c = 0; c < NCHUNK; ++c) {
        const size_t idx = ((size_t)b * NCHUNK + c) * HH + h;
        P[idx] = make_float2(pre, pim);
        const float2 e = E[idx];
        const float nre = lre * pre - lim * pim + e.x;
        const float nim = lre * pim + lim * pre + e.y;
        pre = nre; pim = nim;
    }
}

// ---- K3: fixup y_t += lam^{t+1} * P, unpack f16 -> f32, in place over out ----
__global__ __launch_bounds__(512) void fixup_kernel(const float2* __restrict__ P,
                                                    const float* __restrict__ nu,
                                                    const float* __restrict__ th,
                                                    float* __restrict__ out) {
    const int blk = blockIdx.x;
    const int b   = blk >> 6;
    const int c   = blk & 63;
    const int h   = threadIdx.x;
    const float env  = __expf(nu[h]);
    const float rad  = __expf(-env);
    const float lre  = rad * __cosf(th[h]);
    const float lim_ = rad * __sinf(th[h]);
    const float2 p = P[(size_t)blk * HH + h];
    float zR = p.x, zI = p.y;
    const size_t m0 = (size_t)b * SS + (size_t)c * CHUNK;
    uint32_t* oy = (uint32_t*)out;
#pragma unroll 8
    for (int t = 0; t < CHUNK; ++t) {
        const size_t row = m0 + (size_t)t;
        union { half2v hh; uint32_t u; } pk;
        pk.u = oy[row * NNC + h];
        const float nzR = lre * zR - lim_ * zI;
        zI = lre * zI + lim_ * zR;
        zR = nzR;
        out[row * NNC + h]      = (float)pk.hh[0] + zR;
        out[row * NNC + HH + h] = (float)pk.hh[1] + zI;
    }
}

extern "C" void kernel_launch(void* const* d_in, const int* in_sizes, int n_in,
                              void* d_out, int out_size, void* d_ws, size_t ws_size,
                              hipStream_t stream) {
    const float* x   = (const float*)d_in[0];
    const float* nu  = (const float*)d_in[1];
    const float* th  = (const float*)d_in[2];
    const float* Bre = (const float*)d_in[3];
    const float* Bim = (const float*)d_in[4];
    float* out = (float*)d_out;

    // ws layout: Bc f16 [1024][256] (512 KiB) | E float2 (4 MiB) | P float2 (4 MiB)
    char* ws = (char*)d_ws;
    _Float16* Bc = (_Float16*)ws;
    float2* E = (float2*)(ws + (size_t)NNC * II * sizeof(_Float16));
    float2* P = E + (size_t)NBLK * HH;

    cvt_b_kernel<<<(NNC * II) / 256, 256, 0, stream>>>(Bre, Bim, Bc);
    lru_gemm_scan_kernel<<<NBLK, 512, 0, stream>>>(x, Bc, nu, th, E, (uint32_t*)out);
    scan_carry<<<BB, 512, 0, stream>>>(E, nu, th, P);
    fixup_kernel<<<NBLK, 512, 0, stream>>>(P, nu, th, out);
}

// Round 4
// 101.029 us; speedup vs baseline: 7.1548x; 1.5318x over previous
//
#include <hip/hip_runtime.h>
#include <cstdint>
#include <cstddef>

// (B_, S, I, H) = (16, 2048, 256, 512)
#define BB 16
#define SS 2048
#define II 256
#define HH 512
#define MM (BB * SS)        /* 32768 GEMM rows        */
#define NNC 1024            /* out row width (re|im)  */
#define CHUNK 64
#define NCHUNK (SS / CHUNK) /* 32 chunks per batch    */

using bf16x8 = __attribute__((ext_vector_type(8))) short;
using short8 = __attribute__((ext_vector_type(8))) short;
using f32x4  = __attribute__((ext_vector_type(4))) float;

typedef __attribute__((address_space(3))) uint32_t       lds_u32;
typedef __attribute__((address_space(1))) const uint32_t glb_u32;

__device__ __forceinline__ short f2bf(float f) {
    uint32_t u = __float_as_uint(f);
    u += 0x7fffu + ((u >> 16) & 1u);   // RTNE
    return (short)(u >> 16);
}
__device__ __forceinline__ uint32_t packf16(float a, float b) {
    union { _Float16 h[2]; uint32_t u; } cv;
    cv.h[0] = (_Float16)a; cv.h[1] = (_Float16)b;
    return cv.u;
}
__device__ __forceinline__ float2 unpackf16(uint32_t u) {
    union { uint32_t u; _Float16 h[2]; } cv; cv.u = u;
    return make_float2((float)cv.h[0], (float)cv.h[1]);
}

// ---- x f32 -> bf16, 8 elems/thread ----
__global__ __launch_bounds__(256) void cvt_x(const float4* __restrict__ x,
                                             short8* __restrict__ xb) {
    int i = blockIdx.x * 256 + threadIdx.x;     // 1,048,576 threads exactly
    float4 v0 = x[2 * i], v1 = x[2 * i + 1];
    short8 o;
    o[0]=f2bf(v0.x); o[1]=f2bf(v0.y); o[2]=f2bf(v0.z); o[3]=f2bf(v0.w);
    o[4]=f2bf(v1.x); o[5]=f2bf(v1.y); o[6]=f2bf(v1.z); o[7]=f2bf(v1.w);
    xb[i] = o;
}

// ---- B -> bf16 with re/im rows interleaved: row 2h = B_re[h], 2h+1 = B_im[h] ----
__global__ __launch_bounds__(256) void cvt_b(const float* __restrict__ Bre,
                                             const float* __restrict__ Bim,
                                             short* __restrict__ Bc) {
    int idx = blockIdx.x * 256 + threadIdx.x;   // 32768 threads (1024 rows x 4 chunks of 8)
    int row = idx >> 5;                          // 0..1023
    int k0  = (idx & 31) << 3;                   // 0..248
    const float* src = ((row & 1) ? Bim : Bre) + (size_t)(row >> 1) * II + k0;
    float4 v0 = *(const float4*)src;
    float4 v1 = *(const float4*)(src + 4);
    short8 o;
    o[0]=f2bf(v0.x); o[1]=f2bf(v0.y); o[2]=f2bf(v0.z); o[3]=f2bf(v0.w);
    o[4]=f2bf(v1.x); o[5]=f2bf(v1.y); o[6]=f2bf(v1.z); o[7]=f2bf(v1.w);
    *(short8*)(Bc + (size_t)row * II + k0) = o;
}

// ---- GEMM: Y[m][h] = packf16(sum_k Xb[m][k]*Bc[2h][k], sum_k Xb[m][k]*Bc[2h+1][k])
// m97 structure: 128x128 tile, BK=32, global_load_lds staging, double buffer.
__global__ __launch_bounds__(256, 3) void gemm_pack(const short* __restrict__ Xb,
                                                    const short* __restrict__ Bc,
                                                    uint32_t* __restrict__ Y) {
    __shared__ short Al[2][128 * 32];
    __shared__ short Bl[2][128 * 32];

    const int mt = blockIdx.x >> 3;          // 256 M-tiles
    const int nt = blockIdx.x & 7;           // 8 N-tiles
    const int m0 = mt * 128, n0 = nt * 128;
    const int t  = threadIdx.x;
    const int w  = t >> 6, l = t & 63;
    const int fr = l & 15, fg = l >> 4;
    const int wr = w >> 1, wc = w & 1;

    f32x4 acc[4][4] = {};

    // prologue: stage k-step 0
#pragma unroll
    for (int i = 0; i < 2; ++i) {
        const int ch = i * 256 + t;          // 0..511 ; row = ch/4, koff = (ch&3)*8
        __builtin_amdgcn_global_load_lds(
            (glb_u32*)(Xb + (size_t)(m0 + (ch >> 2)) * II + ((ch & 3) << 3)),
            (lds_u32*)&Al[0][ch * 8], 16, 0, 0);
        __builtin_amdgcn_global_load_lds(
            (glb_u32*)(Bc + (size_t)(n0 + (ch >> 2)) * II + ((ch & 3) << 3)),
            (lds_u32*)&Bl[0][ch * 8], 16, 0, 0);
    }
    __syncthreads();

    for (int ks = 0; ks < 8; ++ks) {         // K = 8 * 32
        const int cur = ks & 1, nxt = cur ^ 1;
        if (ks < 7) {
#pragma unroll
            for (int i = 0; i < 2; ++i) {
                const int ch = i * 256 + t;
                __builtin_amdgcn_global_load_lds(
                    (glb_u32*)(Xb + (size_t)(m0 + (ch >> 2)) * II + (ks + 1) * 32 + ((ch & 3) << 3)),
                    (lds_u32*)&Al[nxt][ch * 8], 16, 0, 0);
                __builtin_amdgcn_global_load_lds(
                    (glb_u32*)(Bc + (size_t)(n0 + (ch >> 2)) * II + (ks + 1) * 32 + ((ch & 3) << 3)),
                    (lds_u32*)&Bl[nxt][ch * 8], 16, 0, 0);
            }
        }
        bf16x8 a[4], b[4];
#pragma unroll
        for (int mi = 0; mi < 4; ++mi)
            a[mi] = *(const bf16x8*)&Al[cur][(wr * 64 + mi * 16 + fr) * 32 + fg * 8];
#pragma unroll
        for (int ni = 0; ni < 4; ++ni)
            b[ni] = *(const bf16x8*)&Bl[cur][(wc * 64 + ni * 16 + fr) * 32 + fg * 8];
#pragma unroll
        for (int mi = 0; mi < 4; ++mi)
#pragma unroll
            for (int ni = 0; ni < 4; ++ni)
                acc[mi][ni] = __builtin_amdgcn_mfma_f32_16x16x32_bf16(
                    a[mi], b[ni], acc[mi][ni], 0, 0, 0);
        __syncthreads();
    }

    // epilogue: D col = lane&15 (C-col), row = fg*4 + reg. Pair cols (2h, 2h+1).
#pragma unroll
    for (int mi = 0; mi < 4; ++mi)
#pragma unroll
        for (int ni = 0; ni < 4; ++ni) {
            const int row0 = m0 + wr * 64 + mi * 16 + fg * 4;
            const int ncol = n0 + wc * 64 + ni * 16 + fr;
#pragma unroll
            for (int r = 0; r < 4; ++r) {
                float v = acc[mi][ni][r];
                float o = __shfl_xor(v, 1);              // partner col's value
                if (!(fr & 1))
                    Y[(size_t)(row0 + r) * HH + (ncol >> 1)] = packf16(v, o);
            }
        }
}

// ---- local chunk scan (h0=0) over packed Y -> chunk-end state E ----
__global__ __launch_bounds__(512) void scan_e(const uint32_t* __restrict__ Y,
                                              const float* __restrict__ nu,
                                              const float* __restrict__ th,
                                              float2* __restrict__ E) {
    const int g = blockIdx.x;                 // 512 = 16 b * 32 c
    const int b = g >> 5, c = g & 31;
    const int h = threadIdx.x;
    const float env = __expf(nu[h]);
    const float rad = __expf(-env);
    float s, cs; __sincosf(th[h], &s, &cs);
    const float lre = rad * cs, lim = rad * s;
    const uint32_t* base = Y + ((size_t)b * SS + (size_t)c * CHUNK) * HH + h;
    float hre = 0.f, him = 0.f;
#pragma unroll 8
    for (int t = 0; t < CHUNK; ++t) {
        float2 y = unpackf16(base[(size_t)t * HH]);
        const float nr = lre * hre - lim * him + y.x;
        him = lre * him + lim * hre + y.y;
        hre = nr;
    }
    E[(size_t)g * HH + h] = make_float2(hre, him);
}

// ---- serial carry across chunks: P[c] = state entering chunk c ----
__global__ __launch_bounds__(512) void carry(const float2* __restrict__ E,
                                             const float* __restrict__ nu,
                                             const float* __restrict__ th,
                                             float2* __restrict__ P) {
    const int b = blockIdx.x;                 // 16
    const int h = threadIdx.x;                // 512
    const float env = __expf(nu[h]);
    const float rL  = __expf(-(float)CHUNK * env);
    float s, cs; __sincosf((float)CHUNK * th[h], &s, &cs);
    const float lre = rL * cs, lim = rL * s;
    float pre = 0.f, pim = 0.f;
#pragma unroll 4
    for (int c = 0; c < NCHUNK; ++c) {
        const size_t idx = ((size_t)b * NCHUNK + c) * HH + h;
        P[idx] = make_float2(pre, pim);
        const float2 e = E[idx];
        const float nr = lre * pre - lim * pim + e.x;
        pim = lre * pim + lim * pre + e.y;
        pre = nr;
    }
}

// ---- final scan seeded with P; write out f32 re|im once ----
__global__ __launch_bounds__(512) void scan_final(const uint32_t* __restrict__ Y,
                                                  const float2* __restrict__ P,
                                                  const float* __restrict__ nu,
                                                  const float* __restrict__ th,
                                                  float* __restrict__ out) {
    const int g = blockIdx.x;
    const int b = g >> 5, c = g & 31;
    const int h = threadIdx.x;
    const float env = __expf(nu[h]);
    const float rad = __expf(-env);
    float s, cs; __sincosf(th[h], &s, &cs);
    const float lre = rad * cs, lim = rad * s;
    const float2 p = P[(size_t)g * HH + h];
    float hre = p.x, him = p.y;
    const uint32_t* yb = Y + ((size_t)b * SS + (size_t)c * CHUNK) * HH + h;
    float* ob = out + ((size_t)b * SS + (size_t)c * CHUNK) * NNC;
#pragma unroll 4
    for (int t = 0; t < CHUNK; ++t) {
        float2 y = unpackf16(yb[(size_t)t * HH]);
        const float nr = lre * hre - lim * him + y.x;
        him = lre * him + lim * hre + y.y;
        hre = nr;
        ob[(size_t)t * NNC + h]      = hre;
        ob[(size_t)t * NNC + HH + h] = him;
    }
}

extern "C" void kernel_launch(void* const* d_in, const int* in_sizes, int n_in,
                              void* d_out, int out_size, void* d_ws, size_t ws_size,
                              hipStream_t stream) {
    const float* x   = (const float*)d_in[0];
    const float* nu  = (const float*)d_in[1];
    const float* th  = (const float*)d_in[2];
    const float* Bre = (const float*)d_in[3];
    const float* Bim = (const float*)d_in[4];
    float* out = (float*)d_out;

    // ws: Xb bf16 16 MiB | Bc bf16 512 KiB | Y u32 64 MiB | E 2 MiB | P 2 MiB
    char* ws = (char*)d_ws;
    short*    Xb = (short*)ws;
    short*    Bc = (short*)(ws + (size_t)MM * II * 2);
    uint32_t* Y  = (uint32_t*)(ws + (size_t)MM * II * 2 + (size_t)NNC * II * 2);
    float2*   E  = (float2*)((char*)Y + (size_t)MM * HH * 4);
    float2*   P  = E + (size_t)BB * NCHUNK * HH;

    cvt_x<<<(MM * II / 8) / 256, 256, 0, stream>>>((const float4*)x, (short8*)Xb);
    cvt_b<<<(NNC * II / 8) / 256, 256, 0, stream>>>(Bre, Bim, Bc);
    gemm_pack<<<(MM / 128) * (NNC / 128), 256, 0, stream>>>(Xb, Bc, Y);
    scan_e<<<BB * NCHUNK, HH, 0, stream>>>(Y, nu, th, E);
    carry<<<BB, HH, 0, stream>>>(E, nu, th, P);
    scan_final<<<BB * NCHUNK, HH, 0, stream>>>(Y, P, nu, th, out);
}